// Round 1
// baseline (1265.946 us; speedup 1.0000x reference)
//
#include <hip/hip_runtime.h>

typedef unsigned short u16;
typedef unsigned int   u32;
typedef __bf16  bf16x8 __attribute__((ext_vector_type(8)));
typedef float   floatx4 __attribute__((ext_vector_type(4)));

#define NP_ALL 304096
#define NP_H01 104096
#define NA_ALL 154096
#define NA_H01 54096

// CSR segment bases in the concatenated deg/rowptr array
#define SEG_C0 0
#define SEG_W0 104096
#define SEG_R0 208192
#define SEG_C1 262288
#define SEG_W1 366384
#define SCAN_N 470480
#define SCAN_NBLK 1838   // ceil(SCAN_N/256)

__device__ __forceinline__ u16 f2bf(float f){
    u32 u = __float_as_uint(f);
    return (u16)((u + 0x7fffu + ((u>>16)&1u)) >> 16);   // RNE
}
__device__ __forceinline__ float blo(u32 v){ return __uint_as_float(v<<16); }
__device__ __forceinline__ float bhi(u32 v){ return __uint_as_float(v & 0xFFFF0000u); }

// ---------- weight / feature prep ----------
__global__ void wcvt_k(u16* __restrict__ dst, const float* __restrict__ src, int n){
    int t = blockIdx.x*256 + threadIdx.x;
    if (t < n) dst[t] = f2bf(src[t]);
}
__global__ void wadd_k(u16* __restrict__ dst, const float* __restrict__ a, const float* __restrict__ b, int n){
    int t = blockIdx.x*256 + threadIdx.x;
    if (t < n) dst[t] = f2bf(a[t] + b[t]);
}
__global__ void bias_k(float* __restrict__ dst, const float* __restrict__ a, const float* __restrict__ b, int n){
    int t = blockIdx.x*256 + threadIdx.x;
    if (t < n) dst[t] = a[t] + (b ? b[t] : 0.0f);
}
// f32 pairs -> packed bf16 (one u32 per thread)
__global__ void cvt2_k(u32* __restrict__ dst, const float* __restrict__ src, int n2){
    int t = blockIdx.x*256 + threadIdx.x;
    if (t >= n2) return;
    dst[t] = (u32)f2bf(src[2*t]) | ((u32)f2bf(src[2*t+1])<<16);
}
// repack bf16 W (K x N row-major) into MFMA B-fragment order
__global__ void repack_k(const u16* __restrict__ Wc, int K, int N, u16* __restrict__ Wp){
    int t = blockIdx.x*256 + threadIdx.x;
    int total = (K>>5)*(N>>4)*64;
    if (t >= total) return;
    int lane = t & 63;
    int nt = (t>>6) % (N>>4);
    int kt = (t>>6) / (N>>4);
    int n  = nt*16 + (lane & 15);
    int k0 = kt*32 + (lane>>4)*8;
    u16* dst = Wp + (size_t)t*8;
    #pragma unroll
    for (int j=0;j<8;j++) dst[j] = Wc[(size_t)(k0+j)*N + n];
}

// ---------- CSR build ----------
__global__ void hist_k(const int* __restrict__ edst, int nE, int limit, int* __restrict__ deg){
    int t = blockIdx.x*256 + threadIdx.x;
    if (t >= nE) return;
    int d = edst[t];
    if (d < limit) atomicAdd(deg + d, 1);
}
__global__ void scan1_k(const int* __restrict__ deg, int* __restrict__ bsum){
    __shared__ int sm[256];
    int t = blockIdx.x*256 + threadIdx.x;
    sm[threadIdx.x] = (t < SCAN_N) ? deg[t] : 0;
    __syncthreads();
    for (int s=128; s>0; s>>=1){
        if (threadIdx.x < s) sm[threadIdx.x] += sm[threadIdx.x+s];
        __syncthreads();
    }
    if (threadIdx.x == 0) bsum[blockIdx.x] = sm[0];
}
__global__ void scan2_k(int* __restrict__ bsum, int n){
    __shared__ int sm[256];
    int chunk = (n + 255) >> 8;
    int st = threadIdx.x * chunk;
    int sum = 0;
    for (int i=0;i<chunk;i++){ int idx = st+i; if (idx < n) sum += bsum[idx]; }
    sm[threadIdx.x] = sum; __syncthreads();
    int acc = sum;
    for (int s=1; s<256; s<<=1){
        int t2 = (threadIdx.x >= s) ? sm[threadIdx.x - s] : 0;
        __syncthreads();
        acc += t2; sm[threadIdx.x] = acc;
        __syncthreads();
    }
    int excl = acc - sum;
    for (int i=0;i<chunk;i++){
        int idx = st+i;
        if (idx < n){ int v = bsum[idx]; bsum[idx] = excl; excl += v; }
    }
}
__global__ void scan3_k(const int* __restrict__ deg, const int* __restrict__ bsum,
                        int* __restrict__ rowptr, int* __restrict__ wp){
    __shared__ int sm[256];
    int t = blockIdx.x*256 + threadIdx.x;
    int v = (t < SCAN_N) ? deg[t] : 0;
    sm[threadIdx.x] = v; __syncthreads();
    int acc = v;
    for (int s=1; s<256; s<<=1){
        int t2 = (threadIdx.x >= s) ? sm[threadIdx.x - s] : 0;
        __syncthreads();
        acc += t2; sm[threadIdx.x] = acc;
        __syncthreads();
    }
    int excl = acc - v + bsum[blockIdx.x];
    if (t < SCAN_N){ rowptr[t] = excl; wp[t] = excl; }
    if (t == SCAN_N-1) rowptr[SCAN_N] = excl + v;
}
__global__ void fill_k(const int* __restrict__ esrc, const int* __restrict__ edst,
                       int nE, int limit, int* __restrict__ wp, int* __restrict__ pool){
    int t = blockIdx.x*256 + threadIdx.x;
    if (t >= nE) return;
    int d = edst[t];
    if (d >= limit) return;
    int p = atomicAdd(wp + d, 1);
    pool[p] = esrc[t];
}

// ---------- gather: mean over in-edges, bf16 sources, bf16 output row ----------
template<int D>
__device__ __forceinline__ void gather_mean(
    const u16* __restrict__ src, int ld,
    const int* __restrict__ rowptr, int seg, int d,
    const int* __restrict__ pool, int lane, u16* __restrict__ outrow)
{
    int b = rowptr[seg + d], e = rowptr[seg + d + 1];
    float rc = 1.0f / (float)((e - b) > 1 ? (e - b) : 1);
    if (D == 128) {
        float a0=0,a1=0,c0=0,c1=0;
        int i = b;
        for (; i+1 < e; i += 2){
            int s0 = pool[i], s1 = pool[i+1];
            u32 v0 = *(const u32*)(src + (size_t)s0*ld + 2*lane);
            u32 v1 = *(const u32*)(src + (size_t)s1*ld + 2*lane);
            a0 += blo(v0); a1 += bhi(v0);
            c0 += blo(v1); c1 += bhi(v1);
        }
        if (i < e){
            int s0 = pool[i];
            u32 v0 = *(const u32*)(src + (size_t)s0*ld + 2*lane);
            a0 += blo(v0); a1 += bhi(v0);
        }
        u32 lo = f2bf((a0+c0)*rc), hi = f2bf((a1+c1)*rc);
        *(u32*)(outrow + 2*lane) = lo | (hi<<16);
    } else {
        float a0=0,a1=0,a2=0,a3=0,c0=0,c1=0,c2=0,c3=0;
        int i = b;
        for (; i+1 < e; i += 2){
            int s0 = pool[i], s1 = pool[i+1];
            uint2 v0 = *(const uint2*)(src + (size_t)s0*ld + 4*lane);
            uint2 v1 = *(const uint2*)(src + (size_t)s1*ld + 4*lane);
            a0 += blo(v0.x); a1 += bhi(v0.x); a2 += blo(v0.y); a3 += bhi(v0.y);
            c0 += blo(v1.x); c1 += bhi(v1.x); c2 += blo(v1.y); c3 += bhi(v1.y);
        }
        if (i < e){
            int s0 = pool[i];
            uint2 v0 = *(const uint2*)(src + (size_t)s0*ld + 4*lane);
            a0 += blo(v0.x); a1 += bhi(v0.x); a2 += blo(v0.y); a3 += bhi(v0.y);
        }
        uint2 o;
        o.x = (u32)f2bf((a0+c0)*rc) | ((u32)f2bf((a1+c1)*rc)<<16);
        o.y = (u32)f2bf((a2+c2)*rc) | ((u32)f2bf((a3+c3)*rc)<<16);
        *(uint2*)(outrow + 4*lane) = o;
    }
}

// L0 paper: Ap[d] = [mean_cites | mean_writes | x_paper[d]]  (384 cols)
__global__ __launch_bounds__(256) void gAp_k(
    const u16* __restrict__ xpb, const u16* __restrict__ xab,
    const int* __restrict__ rowptr, const int* __restrict__ pool,
    u16* __restrict__ Ap)
{
    int gid = blockIdx.x*256 + threadIdx.x;
    int wid = gid >> 6, lane = gid & 63;
    if (wid >= NP_H01) return;
    u16* row = Ap + (size_t)wid*384;
    gather_mean<128>(xpb, 128, rowptr, SEG_C0, wid, pool, lane, row);
    gather_mean<128>(xab, 128, rowptr, SEG_W0, wid, pool, lane, row + 128);
    *(u32*)(row + 256 + 2*lane) = *(const u32*)(xpb + (size_t)wid*128 + 2*lane);
}
// L0 author: Aa[d] = [mean_rev | x_author[d]]  (256 cols)
__global__ __launch_bounds__(256) void gAa_k(
    const u16* __restrict__ xpb, const u16* __restrict__ xab,
    const int* __restrict__ rowptr, const int* __restrict__ pool,
    u16* __restrict__ Aa)
{
    int gid = blockIdx.x*256 + threadIdx.x;
    int wid = gid >> 6, lane = gid & 63;
    if (wid >= NA_H01) return;
    u16* row = Aa + (size_t)wid*256;
    gather_mean<128>(xpb, 128, rowptr, SEG_R0, wid, pool, lane, row);
    *(u32*)(row + 128 + 2*lane) = *(const u32*)(xab + (size_t)wid*128 + 2*lane);
}
// L1: A1[d] cols 0..511 = [mean_c1(xp) | mean_w1(xa)]; cols 512..767 = xp
__global__ __launch_bounds__(256) void gA1_k(
    const u16* __restrict__ xp, const u16* __restrict__ xa,
    const int* __restrict__ rowptr, const int* __restrict__ pool,
    u16* __restrict__ A1)
{
    int gid = blockIdx.x*256 + threadIdx.x;
    int wid = gid >> 6, lane = gid & 63;
    if (wid >= NP_H01) return;
    u16* row = A1 + (size_t)wid*768;
    gather_mean<256>(xp, 768, rowptr, SEG_C1, wid, pool, lane, row);
    gather_mean<256>(xa, 256, rowptr, SEG_W1, wid, pool, lane, row + 256);
}

// ---------- MFMA GEMM v3: 1-barrier software pipeline ----------
// Double-buffered LDS B (global_load_lds, counted vmcnt) + register-prefetched A.
// Per BK=64 stage: wait own vmcnt(8) [retires older B-staging], raw s_barrier,
// issue B(s+1)->other buf + A(s+1)->other reg set, compute stage s.
// The 12 next-stage loads stay IN FLIGHT across the barrier (T3/T4 mechanism) —
// no vmcnt(0) drain anywhere in the main loop.
template<int WROWS, int WCOLS, int WMT, int WNT, bool RELU, bool F32OUT>
__global__ __launch_bounds__(256, 2) void gemm3_k(
    const u16* __restrict__ A, int lda, int M, int K,
    const u16* __restrict__ Wp, int nt16, const float* __restrict__ bias,
    void* __restrict__ C_, int ldc)
{
    constexpr int BNT  = WCOLS*WNT;      // n-tiles per block
    constexpr int BM   = WROWS*WMT*16;
    constexpr int NSTG = 2*BNT;          // frag-groups (1 KB each) per BK=64 stage
    constexpr int PERW = NSTG/4;
    static_assert(2*WMT == 8, "vmcnt(8) literal assumes 8 A-loads per stage");
    __shared__ __align__(16) u16 ldsB[2*NSTG*512];   // double buffer

    int wave = threadIdx.x >> 6, lane = threadIdx.x & 63;
    int quad = lane >> 4, l15 = lane & 15;
    int wr = wave / WCOLS, wc = wave % WCOLS;
    int bm0 = blockIdx.x * BM;
    int ntb = blockIdx.y * BNT;

    floatx4 acc[WMT][WNT];
    #pragma unroll
    for (int i=0;i<WMT;i++)
        #pragma unroll
        for (int j=0;j<WNT;j++) acc[i][j] = (floatx4){0.f,0.f,0.f,0.f};

    const u16* Abase[WMT];               // clamped row base + quad k-offset
    #pragma unroll
    for (int i=0;i<WMT;i++){
        int r = bm0 + (wr*WMT + i)*16 + l15;
        r = (r < M) ? r : (M-1);
        Abase[i] = A + (size_t)r*lda + quad*8;
    }

    int nstages = K >> 6;                // K in {256,384,768} -> even stage count

    auto stage_issue = [&](int sn, int bufsel){
        #pragma unroll
        for (int i=0;i<PERW;i++){
            int g = wave*PERW + i;
            int ktl = g / BNT, ntl = g % BNT;
            const u16* gp = Wp + ((size_t)(sn*2+ktl)*nt16 + ntb + ntl)*512 + lane*8;
            u16* lp = ldsB + bufsel*(NSTG*512) + g*512 + lane*8;
            __builtin_amdgcn_global_load_lds(
                (const __attribute__((address_space(1))) void*)gp,
                (__attribute__((address_space(3))) void*)lp, 16, 0, 0);
        }
    };
    auto a_issue = [&](int sn, bf16x8 (&dst)[2][WMT]){
        #pragma unroll
        for (int ktl=0; ktl<2; ktl++)
            #pragma unroll
            for (int i=0;i<WMT;i++)
                dst[ktl][i] = *(const bf16x8*)(Abase[i] + (size_t)sn*64 + ktl*32);
    };
    auto compute = [&](int bufsel, bf16x8 (&af)[2][WMT]){
        const u16* lb = ldsB + bufsel*(NSTG*512);
        #pragma unroll
        for (int ktl=0; ktl<2; ktl++){
            bf16x8 bfr[WNT];
            #pragma unroll
            for (int j=0;j<WNT;j++)
                bfr[j] = *(const bf16x8*)(lb + ((size_t)(ktl*BNT + wc*WNT + j)*64 + lane)*8);
            #pragma unroll
            for (int i=0;i<WMT;i++)
                #pragma unroll
                for (int j=0;j<WNT;j++)
                    acc[i][j] = __builtin_amdgcn_mfma_f32_16x16x32_bf16(af[ktl][i], bfr[j], acc[i][j], 0,0,0);
        }
    };

    bf16x8 aA[2][WMT], aB[2][WMT];
    // prologue: stage 0 B -> buf0, A(0) -> aA   (12 loads in flight)
    stage_issue(0, 0);
    __builtin_amdgcn_sched_barrier(0);   // pin: staging issued before A loads (vmcnt order)
    a_issue(0, aA);
    __builtin_amdgcn_sched_barrier(0);

    for (int s=0; s<nstages; s+=2){
        // ---- half 0: compute stage s (buf0/aA), prefetch s+1 (buf1/aB) ----
        asm volatile("s_waitcnt lgkmcnt(0)" ::: "memory");  // drain prior ds_reads (WAR)
        asm volatile("s_waitcnt vmcnt(8)"  ::: "memory");   // own B-staging(s) landed
        __builtin_amdgcn_sched_barrier(0);
        __builtin_amdgcn_s_barrier();                       // all waves: buf0 ready, prior reads done
        {
            int sn = s+1;                                   // s+1 < nstages always (nstages even)
            stage_issue(sn, 1);
            __builtin_amdgcn_sched_barrier(0);
            a_issue(sn, aB);
            __builtin_amdgcn_sched_barrier(0);
            compute(0, aA);
        }
        // ---- half 1: compute stage s+1 (buf1/aB), prefetch s+2 (buf0/aA) ----
        asm volatile("s_waitcnt lgkmcnt(0)" ::: "memory");
        asm volatile("s_waitcnt vmcnt(8)"  ::: "memory");
        __builtin_amdgcn_sched_barrier(0);
        __builtin_amdgcn_s_barrier();
        {
            int sn = (s+2 < nstages) ? s+2 : 0;             // tail: dummy valid-address prefetch
            stage_issue(sn, 0);
            __builtin_amdgcn_sched_barrier(0);
            a_issue(sn, aA);
            __builtin_amdgcn_sched_barrier(0);
            compute(1, aB);
        }
    }
    // dummy tail prefetch must land before LDS dealloc at endpgm
    asm volatile("s_waitcnt vmcnt(0)" ::: "memory");

    // epilogue: D layout col=lane&15, row=quad*4+ii
    #pragma unroll
    for (int j=0;j<WNT;j++){
        int col = (ntb + wc*WNT + j)*16 + l15;
        float bv = bias[col];
        #pragma unroll
        for (int i=0;i<WMT;i++){
            int rbase = bm0 + (wr*WMT + i)*16 + quad*4;
            #pragma unroll
            for (int ii=0; ii<4; ii++){
                int row = rbase + ii;
                if (row < M){
                    float v = acc[i][j][ii] + bv;
                    if (RELU) v = fmaxf(v, 0.0f);
                    if (F32OUT) ((float*)C_)[(size_t)row*ldc + col] = v;
                    else        ((u16*)C_)[(size_t)row*ldc + col] = f2bf(v);
                }
            }
        }
    }
}

extern "C" void kernel_launch(void* const* d_in, const int* in_sizes, int n_in,
                              void* d_out, int out_size, void* d_ws, size_t ws_size,
                              hipStream_t stream)
{
    const float* x_paper  = (const float*)d_in[0];
    const float* x_author = (const float*)d_in[1];
    const float* w_in[22];
    for (int i=0;i<22;i++) w_in[i] = (const float*)d_in[i];
    const int* e_c1 = (const int*)d_in[22]; int nE_c1 = in_sizes[22]/2;
    const int* e_c2 = (const int*)d_in[23]; int nE_c2 = in_sizes[23]/2;
    const int* e_w1 = (const int*)d_in[24]; int nE_w1 = in_sizes[24]/2;
    const int* e_w2 = (const int*)d_in[25]; int nE_w2 = in_sizes[25]/2;
    const int* e_r1 = (const int*)d_in[26]; int nE_r1 = in_sizes[26]/2;
    const int* e_r2 = (const int*)d_in[27]; int nE_r2 = in_sizes[27]/2;
    float* out = (float*)d_out;

    // ---- workspace layout (~320 MB peak) ----
    size_t off = 0;
    auto take = [&](size_t nb)->void* {
        void* p = (char*)d_ws + off;
        off = (off + nb + 255) & ~(size_t)255;
        return p;
    };
    u16*   A1  = (u16*)take((size_t)NP_H01*768*2); // L1 A; early life: xpb|xab overlay
    u16*   xa  = (u16*)take((size_t)NA_H01*256*2); // L0 author output (bf16)
    u16*   Ap  = (u16*)take((size_t)NP_H01*384*2); // L0 paper A; later h1 overlay
    u16*   Aa  = (u16*)take((size_t)NA_H01*256*2); // L0 author A
    int*   deg    = (int*)take((size_t)SCAN_N*4);
    int*   rowptr = (int*)take((size_t)(SCAN_N+1)*4);
    int*   wp     = (int*)take((size_t)SCAN_N*4);
    int*   bsum   = (int*)take((size_t)SCAN_NBLK*4);
    int*   pool   = (int*)take((size_t)4000000*4);
    u16* Wc0p = (u16*)take((size_t)384*256*2);
    u16* Wc0a = (u16*)take((size_t)256*256*2);
    u16* Wc1  = (u16*)take((size_t)768*256*2);
    u16* Wcf  = (u16*)take((size_t)256*64*2);
    u16* Wp0p = (u16*)take((size_t)384*256*2);
    u16* Wp0a = (u16*)take((size_t)256*256*2);
    u16* Wp1  = (u16*)take((size_t)768*256*2);
    u16* Wpf  = (u16*)take((size_t)256*64*2);
    float* b0p = (float*)take(256*4);
    float* b0a = (float*)take(256*4);
    float* b1  = (float*)take(256*4);
    float* bfin= (float*)take(64*4);

    // overlays:
    u16* xpb = A1;                                   // bf16 x_paper  (NP_ALL x 128)
    u16* xab = A1 + (size_t)NP_ALL*128;              // bf16 x_author (NA_ALL x 128)
    u16* h1  = Ap;                                   // L1 hidden, Ap dead after L0 GEMM

    auto cdiv = [](long a, long b){ return (int)((a + b - 1)/b); };
    dim3 B(256);

    // ---- phase 0: zero CSR histogram ----
    hipMemsetAsync(deg, 0, (size_t)SCAN_N*4, stream);

    // ---- phase 1: weight + feature prep ----
    wcvt_k<<<cdiv(32768,256),B,0,stream>>>(Wc0p,        w_in[2], 32768);
    wcvt_k<<<cdiv(32768,256),B,0,stream>>>(Wc0p+32768,  w_in[5], 32768);
    wadd_k<<<cdiv(32768,256),B,0,stream>>>(Wc0p+65536,  w_in[4], w_in[7], 32768);
    wcvt_k<<<cdiv(32768,256),B,0,stream>>>(Wc0a,        w_in[8], 32768);
    wcvt_k<<<cdiv(32768,256),B,0,stream>>>(Wc0a+32768,  w_in[10], 32768);
    wcvt_k<<<cdiv(65536,256),B,0,stream>>>(Wc1,         w_in[11], 65536);
    wcvt_k<<<cdiv(65536,256),B,0,stream>>>(Wc1+65536,   w_in[14], 65536);
    wadd_k<<<cdiv(65536,256),B,0,stream>>>(Wc1+131072,  w_in[13], w_in[16], 65536);
    wcvt_k<<<cdiv(16384,256),B,0,stream>>>(Wcf,         w_in[20], 16384);
    bias_k<<<1,B,0,stream>>>(b0p, w_in[3],  w_in[6],  256);
    bias_k<<<1,B,0,stream>>>(b0a, w_in[9],  nullptr,  256);
    bias_k<<<1,B,0,stream>>>(b1,  w_in[12], w_in[15], 256);
    bias_k<<<1,B,0,stream>>>(bfin,w_in[21], nullptr,  64);
    repack_k<<<cdiv(12288,256),B,0,stream>>>(Wc0p, 384, 256, Wp0p);
    repack_k<<<cdiv( 8192,256),B,0,stream>>>(Wc0a, 256, 256, Wp0a);
    repack_k<<<cdiv(24576,256),B,0,stream>>>(Wc1,  768, 256, Wp1);
    repack_k<<<cdiv( 2048,256),B,0,stream>>>(Wcf,  256,  64, Wpf);
    int n2p = NP_ALL*128/2, n2a = NA_ALL*128/2;
    cvt2_k<<<cdiv(n2p,256),B,0,stream>>>((u32*)xpb, x_paper,  n2p);
    cvt2_k<<<cdiv(n2a,256),B,0,stream>>>((u32*)xab, x_author, n2a);

    // ---- phase 2: CSR build (histogram -> scan -> fill) ----
    hist_k<<<cdiv(nE_c1,256),B,0,stream>>>(e_c1+nE_c1, nE_c1, NP_H01, deg+SEG_C0);
    hist_k<<<cdiv(nE_c2,256),B,0,stream>>>(e_c2+nE_c2, nE_c2, NP_H01, deg+SEG_C0);
    hist_k<<<cdiv(nE_w1,256),B,0,stream>>>(e_w1+nE_w1, nE_w1, NP_H01, deg+SEG_W0);
    hist_k<<<cdiv(nE_w2,256),B,0,stream>>>(e_w2+nE_w2, nE_w2, NP_H01, deg+SEG_W0);
    hist_k<<<cdiv(nE_r1,256),B,0,stream>>>(e_r1+nE_r1, nE_r1, NA_H01, deg+SEG_R0);
    hist_k<<<cdiv(nE_r2,256),B,0,stream>>>(e_r2+nE_r2, nE_r2, NA_H01, deg+SEG_R0);
    hist_k<<<cdiv(nE_c1,256),B,0,stream>>>(e_c1+nE_c1, nE_c1, NP_H01, deg+SEG_C1);
    hist_k<<<cdiv(nE_w1,256),B,0,stream>>>(e_w1+nE_w1, nE_w1, NP_H01, deg+SEG_W1);
    scan1_k<<<SCAN_NBLK,B,0,stream>>>(deg, bsum);
    scan2_k<<<1,B,0,stream>>>(bsum, SCAN_NBLK);
    scan3_k<<<SCAN_NBLK,B,0,stream>>>(deg, bsum, rowptr, wp);
    fill_k<<<cdiv(nE_c1,256),B,0,stream>>>(e_c1, e_c1+nE_c1, nE_c1, NP_H01, wp+SEG_C0, pool);
    fill_k<<<cdiv(nE_c2,256),B,0,stream>>>(e_c2, e_c2+nE_c2, nE_c2, NP_H01, wp+SEG_C0, pool);
    fill_k<<<cdiv(nE_w1,256),B,0,stream>>>(e_w1, e_w1+nE_w1, nE_w1, NP_H01, wp+SEG_W0, pool);
    fill_k<<<cdiv(nE_w2,256),B,0,stream>>>(e_w2, e_w2+nE_w2, nE_w2, NP_H01, wp+SEG_W0, pool);
    fill_k<<<cdiv(nE_r1,256),B,0,stream>>>(e_r1, e_r1+nE_r1, nE_r1, NA_H01, wp+SEG_R0, pool);
    fill_k<<<cdiv(nE_r2,256),B,0,stream>>>(e_r2, e_r2+nE_r2, nE_r2, NA_H01, wp+SEG_R0, pool);
    fill_k<<<cdiv(nE_c1,256),B,0,stream>>>(e_c1, e_c1+nE_c1, nE_c1, NP_H01, wp+SEG_C1, pool);
    fill_k<<<cdiv(nE_w1,256),B,0,stream>>>(e_w1, e_w1+nE_w1, nE_w1, NP_H01, wp+SEG_W1, pool);

    // ---- phase 3: L0 gathers (build Ap, Aa) ----
    gAp_k<<<cdiv((long)NP_H01*64,256),B,0,stream>>>(xpb, xab, rowptr, pool, Ap);
    gAa_k<<<cdiv((long)NA_H01*64,256),B,0,stream>>>(xpb, xab, rowptr, pool, Aa);

    // ---- phase 4: L0 GEMMs (xpb/xab dead now; xp lands in A1 cols 512..767) ----
    {
        dim3 g(cdiv(NP_H01,128), 2);
        gemm3_k<2,2,4,4,true,false><<<g,B,0,stream>>>(Ap, 384, NP_H01, 384, Wp0p, 16, b0p, A1+512, 768);
    }
    {
        dim3 g(cdiv(NA_H01,128), 2);
        gemm3_k<2,2,4,4,true,false><<<g,B,0,stream>>>(Aa, 256, NA_H01, 256, Wp0a, 16, b0a, xa, 256);
    }

    // ---- phase 5: L1 gather (A1 cols 0..511) ----
    gA1_k<<<cdiv((long)NP_H01*64,256),B,0,stream>>>(A1+512, xa, rowptr, pool, A1);

    // ---- phase 6: L1 GEMM (h1 overlays Ap) + final linear (f32 out) ----
    {
        dim3 g(cdiv(NP_H01,128), 2);
        gemm3_k<2,2,4,4,true,false><<<g,B,0,stream>>>(A1, 768, NP_H01, 768, Wp1, 16, b1, h1, 256);
    }
    {
        dim3 g(cdiv(NP_H01,256), 1);
        gemm3_k<4,1,4,4,false,true><<<g,B,0,stream>>>(h1, 256, NP_H01, 256, Wpf, 4, bfin, out, 64);
    }
}

// Round 2
// 1264.583 us; speedup vs baseline: 1.0011x; 1.0011x over previous
//
#include <hip/hip_runtime.h>

typedef unsigned short u16;
typedef unsigned int   u32;
typedef __bf16  bf16x8 __attribute__((ext_vector_type(8)));
typedef float   floatx4 __attribute__((ext_vector_type(4)));

#define NP_ALL 304096
#define NP_H01 104096
#define NA_ALL 154096
#define NA_H01 54096

// CSR segment bases in the concatenated deg/rowptr array
#define SEG_C0 0
#define SEG_W0 104096
#define SEG_R0 208192
#define SEG_C1 262288
#define SEG_W1 366384
#define SCAN_N 470480
#define SCAN_NBLK 1838   // ceil(SCAN_N/256)

__device__ __forceinline__ u16 f2bf(float f){
    u32 u = __float_as_uint(f);
    return (u16)((u + 0x7fffu + ((u>>16)&1u)) >> 16);   // RNE
}
__device__ __forceinline__ float blo(u32 v){ return __uint_as_float(v<<16); }
__device__ __forceinline__ float bhi(u32 v){ return __uint_as_float(v & 0xFFFF0000u); }

// ---------- weight / feature prep ----------
__global__ void wcvt_k(u16* __restrict__ dst, const float* __restrict__ src, int n){
    int t = blockIdx.x*256 + threadIdx.x;
    if (t < n) dst[t] = f2bf(src[t]);
}
__global__ void wadd_k(u16* __restrict__ dst, const float* __restrict__ a, const float* __restrict__ b, int n){
    int t = blockIdx.x*256 + threadIdx.x;
    if (t < n) dst[t] = f2bf(a[t] + b[t]);
}
__global__ void bias_k(float* __restrict__ dst, const float* __restrict__ a, const float* __restrict__ b, int n){
    int t = blockIdx.x*256 + threadIdx.x;
    if (t < n) dst[t] = a[t] + (b ? b[t] : 0.0f);
}
// f32 pairs -> packed bf16 (one u32 per thread)
__global__ void cvt2_k(u32* __restrict__ dst, const float* __restrict__ src, int n2){
    int t = blockIdx.x*256 + threadIdx.x;
    if (t >= n2) return;
    dst[t] = (u32)f2bf(src[2*t]) | ((u32)f2bf(src[2*t+1])<<16);
}
// repack bf16 W (K x N row-major) into MFMA B-fragment order
__global__ void repack_k(const u16* __restrict__ Wc, int K, int N, u16* __restrict__ Wp){
    int t = blockIdx.x*256 + threadIdx.x;
    int total = (K>>5)*(N>>4)*64;
    if (t >= total) return;
    int lane = t & 63;
    int nt = (t>>6) % (N>>4);
    int kt = (t>>6) / (N>>4);
    int n  = nt*16 + (lane & 15);
    int k0 = kt*32 + (lane>>4)*8;
    u16* dst = Wp + (size_t)t*8;
    #pragma unroll
    for (int j=0;j<8;j++) dst[j] = Wc[(size_t)(k0+j)*N + n];
}

// ---------- CSR build ----------
__global__ void hist_k(const int* __restrict__ edst, int nE, int limit, int* __restrict__ deg){
    int t = blockIdx.x*256 + threadIdx.x;
    if (t >= nE) return;
    int d = edst[t];
    if (d < limit) atomicAdd(deg + d, 1);
}
__global__ void scan1_k(const int* __restrict__ deg, int* __restrict__ bsum){
    __shared__ int sm[256];
    int t = blockIdx.x*256 + threadIdx.x;
    sm[threadIdx.x] = (t < SCAN_N) ? deg[t] : 0;
    __syncthreads();
    for (int s=128; s>0; s>>=1){
        if (threadIdx.x < s) sm[threadIdx.x] += sm[threadIdx.x+s];
        __syncthreads();
    }
    if (threadIdx.x == 0) bsum[blockIdx.x] = sm[0];
}
__global__ void scan2_k(int* __restrict__ bsum, int n){
    __shared__ int sm[256];
    int chunk = (n + 255) >> 8;
    int st = threadIdx.x * chunk;
    int sum = 0;
    for (int i=0;i<chunk;i++){ int idx = st+i; if (idx < n) sum += bsum[idx]; }
    sm[threadIdx.x] = sum; __syncthreads();
    int acc = sum;
    for (int s=1; s<256; s<<=1){
        int t2 = (threadIdx.x >= s) ? sm[threadIdx.x - s] : 0;
        __syncthreads();
        acc += t2; sm[threadIdx.x] = acc;
        __syncthreads();
    }
    int excl = acc - sum;
    for (int i=0;i<chunk;i++){
        int idx = st+i;
        if (idx < n){ int v = bsum[idx]; bsum[idx] = excl; excl += v; }
    }
}
__global__ void scan3_k(const int* __restrict__ deg, const int* __restrict__ bsum,
                        int* __restrict__ rowptr, int* __restrict__ wp){
    __shared__ int sm[256];
    int t = blockIdx.x*256 + threadIdx.x;
    int v = (t < SCAN_N) ? deg[t] : 0;
    sm[threadIdx.x] = v; __syncthreads();
    int acc = v;
    for (int s=1; s<256; s<<=1){
        int t2 = (threadIdx.x >= s) ? sm[threadIdx.x - s] : 0;
        __syncthreads();
        acc += t2; sm[threadIdx.x] = acc;
        __syncthreads();
    }
    int excl = acc - v + bsum[blockIdx.x];
    if (t < SCAN_N){ rowptr[t] = excl; wp[t] = excl; }
    if (t == SCAN_N-1) rowptr[SCAN_N] = excl + v;
}
__global__ void fill_k(const int* __restrict__ esrc, const int* __restrict__ edst,
                       int nE, int limit, int* __restrict__ wp, int* __restrict__ pool){
    int t = blockIdx.x*256 + threadIdx.x;
    if (t >= nE) return;
    int d = edst[t];
    if (d >= limit) return;
    int p = atomicAdd(wp + d, 1);
    pool[p] = esrc[t];
}

// ---------- gather: mean over in-edges ----------
// srcl / outl are fully per-lane-resolved pointers; rstride is the source
// row stride in u16 units. Output layout (tiled or row-major) is encoded
// entirely in outl by the caller.
template<int D>
__device__ __forceinline__ void gather_mean(
    const u16* __restrict__ srcl, size_t rstride,
    const int* __restrict__ rowptr, int seg, int d,
    const int* __restrict__ pool, u16* __restrict__ outl)
{
    int b = rowptr[seg + d], e = rowptr[seg + d + 1];
    float rc = 1.0f / (float)((e - b) > 1 ? (e - b) : 1);
    if (D == 128) {
        float a0=0,a1=0,c0=0,c1=0;
        int i = b;
        for (; i+1 < e; i += 2){
            int s0 = pool[i], s1 = pool[i+1];
            u32 v0 = *(const u32*)(srcl + (size_t)s0*rstride);
            u32 v1 = *(const u32*)(srcl + (size_t)s1*rstride);
            a0 += blo(v0); a1 += bhi(v0);
            c0 += blo(v1); c1 += bhi(v1);
        }
        if (i < e){
            int s0 = pool[i];
            u32 v0 = *(const u32*)(srcl + (size_t)s0*rstride);
            a0 += blo(v0); a1 += bhi(v0);
        }
        u32 lo = f2bf((a0+c0)*rc), hi = f2bf((a1+c1)*rc);
        *(u32*)outl = lo | (hi<<16);
    } else {
        float a0=0,a1=0,a2=0,a3=0,c0=0,c1=0,c2=0,c3=0;
        int i = b;
        for (; i+1 < e; i += 2){
            int s0 = pool[i], s1 = pool[i+1];
            uint2 v0 = *(const uint2*)(srcl + (size_t)s0*rstride);
            uint2 v1 = *(const uint2*)(srcl + (size_t)s1*rstride);
            a0 += blo(v0.x); a1 += bhi(v0.x); a2 += blo(v0.y); a3 += bhi(v0.y);
            c0 += blo(v1.x); c1 += bhi(v1.x); c2 += blo(v1.y); c3 += bhi(v1.y);
        }
        if (i < e){
            int s0 = pool[i];
            uint2 v0 = *(const uint2*)(srcl + (size_t)s0*rstride);
            a0 += blo(v0.x); a1 += bhi(v0.x); a2 += blo(v0.y); a3 += bhi(v0.y);
        }
        uint2 o;
        o.x = (u32)f2bf((a0+c0)*rc) | ((u32)f2bf((a1+c1)*rc)<<16);
        o.y = (u32)f2bf((a2+c2)*rc) | ((u32)f2bf((a3+c3)*rc)<<16);
        *(uint2*)outl = o;
    }
}

// All GEMM A-operands use stage-major tiled layout: A_t[kt][M][64] (kt = 64-col
// block). Per-lane element (wid, col): addr = ((col>>6)*M + wid)*64 + (col&63).
// This makes each GEMM K-stage read a CONTIGUOUS slab (DRAM-page-efficient)
// instead of 128B-out-of-every-1536B strided reads.

// L0 paper: Ap_t[wid] = [mean_cites(128) | mean_writes(128) | x_paper(128)], tiled M=NP_H01
__global__ __launch_bounds__(256) void gAp_k(
    const u16* __restrict__ xpb, const u16* __restrict__ xab,
    const int* __restrict__ rowptr, const int* __restrict__ pool,
    u16* __restrict__ Ap)
{
    int gid = blockIdx.x*256 + threadIdx.x;
    int wid = gid >> 6, lane = gid & 63;
    if (wid >= NP_H01) return;
    const size_t SM = (size_t)NP_H01*64;
    size_t wofs = (size_t)wid*64 + 2*(lane&31);
    int hs = lane>>5;                      // 128-col chunk spans 2 stages
    gather_mean<128>(xpb + 2*lane, 128, rowptr, SEG_C0, wid, pool, Ap + (size_t)(0+hs)*SM + wofs);
    gather_mean<128>(xab + 2*lane, 128, rowptr, SEG_W0, wid, pool, Ap + (size_t)(2+hs)*SM + wofs);
    u32 v = *(const u32*)(xpb + (size_t)wid*128 + 2*lane);
    *(u32*)(Ap + (size_t)(4+hs)*SM + wofs) = v;
}
// L0 author: Aa_t[wid] = [mean_rev(128) | x_author(128)], tiled M=NA_H01
__global__ __launch_bounds__(256) void gAa_k(
    const u16* __restrict__ xpb, const u16* __restrict__ xab,
    const int* __restrict__ rowptr, const int* __restrict__ pool,
    u16* __restrict__ Aa)
{
    int gid = blockIdx.x*256 + threadIdx.x;
    int wid = gid >> 6, lane = gid & 63;
    if (wid >= NA_H01) return;
    const size_t SM = (size_t)NA_H01*64;
    size_t wofs = (size_t)wid*64 + 2*(lane&31);
    int hs = lane>>5;
    gather_mean<128>(xpb + 2*lane, 128, rowptr, SEG_R0, wid, pool, Aa + (size_t)(0+hs)*SM + wofs);
    u32 v = *(const u32*)(xab + (size_t)wid*128 + 2*lane);
    *(u32*)(Aa + (size_t)(2+hs)*SM + wofs) = v;
}
// L1: A1_t stages 0..3 = mean_c1(xp), 4..7 = mean_w1(xa), 8..11 = xp (already
// written tiled by the L0p GEMM epilogue). xp is READ tiled from stages 8..11.
__global__ __launch_bounds__(256) void gA1_k(
    const u16* __restrict__ A1src,   // == A1 (stages 8..11 hold xp)
    const u16* __restrict__ xa,      // row-major [NA_H01][256]
    const int* __restrict__ rowptr, const int* __restrict__ pool,
    u16* __restrict__ A1)
{
    int gid = blockIdx.x*256 + threadIdx.x;
    int wid = gid >> 6, lane = gid & 63;
    if (wid >= NP_H01) return;
    const size_t SM = (size_t)NP_H01*64;
    int qs = lane>>4;                      // 256-col chunk spans 4 stages
    size_t wofs = (size_t)wid*64 + 4*(lane&15);
    // cites: src = xp tiled (stages 8..11, rstride 64), out stages 0..3
    gather_mean<256>(A1src + (size_t)(8+qs)*SM + 4*(lane&15), 64,
                     rowptr, SEG_C1, wid, pool, A1 + (size_t)(0+qs)*SM + wofs);
    // writes: src = xa row-major, out stages 4..7
    gather_mean<256>(xa + 4*lane, 256,
                     rowptr, SEG_W1, wid, pool, A1 + (size_t)(4+qs)*SM + wofs);
}

// ---------- MFMA GEMM v4: 1-barrier pipeline + stage-major tiled A ----------
// A is tiled A_t[kt][M][64]: every stage's loads are contiguous (full DRAM
// pages). B staged to LDS via global_load_lds, double-buffered, counted vmcnt.
template<int WROWS, int WCOLS, int WMT, int WNT, bool RELU, bool F32OUT>
__global__ __launch_bounds__(256, 2) void gemm4_k(
    const u16* __restrict__ At, int M, int K,
    const u16* __restrict__ Wp, int nt16, const float* __restrict__ bias,
    void* __restrict__ C_, int ldc, int tileM, int colofs)
{
    constexpr int BNT  = WCOLS*WNT;      // n-tiles per block
    constexpr int BM   = WROWS*WMT*16;
    constexpr int NSTG = 2*BNT;          // frag-groups (1 KB each) per BK=64 stage
    constexpr int PERW = NSTG/4;
    static_assert(2*WMT == 8, "vmcnt(8) literal assumes 8 A-loads per stage");
    __shared__ __align__(16) u16 ldsB[2*NSTG*512];   // double buffer

    int wave = threadIdx.x >> 6, lane = threadIdx.x & 63;
    int quad = lane >> 4, l15 = lane & 15;
    int wr = wave / WCOLS, wc = wave % WCOLS;
    int bm0 = blockIdx.x * BM;
    int ntb = blockIdx.y * BNT;
    const size_t SMS = (size_t)M*64;     // u16 per stage block

    floatx4 acc[WMT][WNT];
    #pragma unroll
    for (int i=0;i<WMT;i++)
        #pragma unroll
        for (int j=0;j<WNT;j++) acc[i][j] = (floatx4){0.f,0.f,0.f,0.f};

    const u16* Abase[WMT];               // tiled: row*64 + quad*8
    #pragma unroll
    for (int i=0;i<WMT;i++){
        int r = bm0 + (wr*WMT + i)*16 + l15;
        r = (r < M) ? r : (M-1);
        Abase[i] = At + (size_t)r*64 + quad*8;
    }

    int nstages = K >> 6;                // K in {256,384,768} -> even stage count

    auto stage_issue = [&](int sn, int bufsel){
        #pragma unroll
        for (int i=0;i<PERW;i++){
            int g = wave*PERW + i;
            int ktl = g / BNT, ntl = g % BNT;
            const u16* gp = Wp + ((size_t)(sn*2+ktl)*nt16 + ntb + ntl)*512 + lane*8;
            u16* lp = ldsB + bufsel*(NSTG*512) + g*512 + lane*8;
            __builtin_amdgcn_global_load_lds(
                (const __attribute__((address_space(1))) void*)gp,
                (__attribute__((address_space(3))) void*)lp, 16, 0, 0);
        }
    };
    auto a_issue = [&](int sn, bf16x8 (&dst)[2][WMT]){
        #pragma unroll
        for (int ktl=0; ktl<2; ktl++)
            #pragma unroll
            for (int i=0;i<WMT;i++)
                dst[ktl][i] = *(const bf16x8*)(Abase[i] + (size_t)sn*SMS + ktl*32);
    };
    auto compute = [&](int bufsel, bf16x8 (&af)[2][WMT]){
        const u16* lb = ldsB + bufsel*(NSTG*512);
        #pragma unroll
        for (int ktl=0; ktl<2; ktl++){
            bf16x8 bfr[WNT];
            #pragma unroll
            for (int j=0;j<WNT;j++)
                bfr[j] = *(const bf16x8*)(lb + ((size_t)(ktl*BNT + wc*WNT + j)*64 + lane)*8);
            #pragma unroll
            for (int i=0;i<WMT;i++)
                #pragma unroll
                for (int j=0;j<WNT;j++)
                    acc[i][j] = __builtin_amdgcn_mfma_f32_16x16x32_bf16(af[ktl][i], bfr[j], acc[i][j], 0,0,0);
        }
    };

    bf16x8 aA[2][WMT], aB[2][WMT];
    // prologue: stage 0 B -> buf0, A(0) -> aA
    stage_issue(0, 0);
    __builtin_amdgcn_sched_barrier(0);   // pin: staging issued before A loads (vmcnt order)
    a_issue(0, aA);
    __builtin_amdgcn_sched_barrier(0);

    for (int s=0; s<nstages; s+=2){
        // ---- half 0: compute stage s (buf0/aA), prefetch s+1 (buf1/aB) ----
        asm volatile("s_waitcnt lgkmcnt(0)" ::: "memory");  // drain prior ds_reads (WAR)
        asm volatile("s_waitcnt vmcnt(8)"  ::: "memory");   // own B-staging(s) landed
        __builtin_amdgcn_sched_barrier(0);
        __builtin_amdgcn_s_barrier();
        {
            int sn = s+1;                                   // s+1 < nstages (nstages even)
            stage_issue(sn, 1);
            __builtin_amdgcn_sched_barrier(0);
            a_issue(sn, aB);
            __builtin_amdgcn_sched_barrier(0);
            compute(0, aA);
        }
        // ---- half 1: compute stage s+1 (buf1/aB), prefetch s+2 (buf0/aA) ----
        asm volatile("s_waitcnt lgkmcnt(0)" ::: "memory");
        asm volatile("s_waitcnt vmcnt(8)"  ::: "memory");
        __builtin_amdgcn_sched_barrier(0);
        __builtin_amdgcn_s_barrier();
        {
            int sn = (s+2 < nstages) ? s+2 : 0;             // tail: dummy valid-address prefetch
            stage_issue(sn, 0);
            __builtin_amdgcn_sched_barrier(0);
            a_issue(sn, aA);
            __builtin_amdgcn_sched_barrier(0);
            compute(1, aB);
        }
    }
    // dummy tail prefetch must land before LDS dealloc at endpgm
    asm volatile("s_waitcnt vmcnt(0)" ::: "memory");

    // epilogue: D layout col=lane&15, row=quad*4+ii
    #pragma unroll
    for (int j=0;j<WNT;j++){
        int col = (ntb + wc*WNT + j)*16 + l15;
        float bv = bias[col];
        #pragma unroll
        for (int i=0;i<WMT;i++){
            int rbase = bm0 + (wr*WMT + i)*16 + quad*4;
            #pragma unroll
            for (int ii=0; ii<4; ii++){
                int row = rbase + ii;
                if (row < M){
                    float v = acc[i][j][ii] + bv;
                    if (RELU) v = fmaxf(v, 0.0f);
                    if (F32OUT) ((float*)C_)[(size_t)row*ldc + col] = v;
                    else if (tileM > 0){
                        int ct = col + colofs;   // tiled bf16 out: [(ct>>6)][row][ct&63]
                        ((u16*)C_)[((size_t)(ct>>6)*tileM + row)*64 + (ct&63)] = f2bf(v);
                    } else {
                        ((u16*)C_)[(size_t)row*ldc + col] = f2bf(v);
                    }
                }
            }
        }
    }
}

extern "C" void kernel_launch(void* const* d_in, const int* in_sizes, int n_in,
                              void* d_out, int out_size, void* d_ws, size_t ws_size,
                              hipStream_t stream)
{
    const float* x_paper  = (const float*)d_in[0];
    const float* x_author = (const float*)d_in[1];
    const float* w_in[22];
    for (int i=0;i<22;i++) w_in[i] = (const float*)d_in[i];
    const int* e_c1 = (const int*)d_in[22]; int nE_c1 = in_sizes[22]/2;
    const int* e_c2 = (const int*)d_in[23]; int nE_c2 = in_sizes[23]/2;
    const int* e_w1 = (const int*)d_in[24]; int nE_w1 = in_sizes[24]/2;
    const int* e_w2 = (const int*)d_in[25]; int nE_w2 = in_sizes[25]/2;
    const int* e_r1 = (const int*)d_in[26]; int nE_r1 = in_sizes[26]/2;
    const int* e_r2 = (const int*)d_in[27]; int nE_r2 = in_sizes[27]/2;
    float* out = (float*)d_out;

    // ---- workspace layout (~320 MB peak) ----
    size_t off = 0;
    auto take = [&](size_t nb)->void* {
        void* p = (char*)d_ws + off;
        off = (off + nb + 255) & ~(size_t)255;
        return p;
    };
    u16*   A1  = (u16*)take((size_t)NP_H01*768*2); // L1 A (tiled); early life: xpb|xab overlay
    u16*   xa  = (u16*)take((size_t)NA_H01*256*2); // L0 author output (bf16 row-major)
    u16*   Ap  = (u16*)take((size_t)NP_H01*384*2); // L0 paper A (tiled); later h1 overlay
    u16*   Aa  = (u16*)take((size_t)NA_H01*256*2); // L0 author A (tiled)
    int*   deg    = (int*)take((size_t)SCAN_N*4);
    int*   rowptr = (int*)take((size_t)(SCAN_N+1)*4);
    int*   wp     = (int*)take((size_t)SCAN_N*4);
    int*   bsum   = (int*)take((size_t)SCAN_NBLK*4);
    int*   pool   = (int*)take((size_t)4000000*4);
    u16* Wc0p = (u16*)take((size_t)384*256*2);
    u16* Wc0a = (u16*)take((size_t)256*256*2);
    u16* Wc1  = (u16*)take((size_t)768*256*2);
    u16* Wcf  = (u16*)take((size_t)256*64*2);
    u16* Wp0p = (u16*)take((size_t)384*256*2);
    u16* Wp0a = (u16*)take((size_t)256*256*2);
    u16* Wp1  = (u16*)take((size_t)768*256*2);
    u16* Wpf  = (u16*)take((size_t)256*64*2);
    float* b0p = (float*)take(256*4);
    float* b0a = (float*)take(256*4);
    float* b1  = (float*)take(256*4);
    float* bfin= (float*)take(64*4);

    // overlays:
    u16* xpb = A1;                                   // bf16 x_paper  (NP_ALL x 128)
    u16* xab = A1 + (size_t)NP_ALL*128;              // bf16 x_author (NA_ALL x 128)
    u16* h1  = Ap;                                   // L1 hidden (tiled), Ap dead after L0 GEMM

    auto cdiv = [](long a, long b){ return (int)((a + b - 1)/b); };
    dim3 B(256);

    // ---- phase 0: zero CSR histogram ----
    hipMemsetAsync(deg, 0, (size_t)SCAN_N*4, stream);

    // ---- phase 1: weight + feature prep ----
    wcvt_k<<<cdiv(32768,256),B,0,stream>>>(Wc0p,        w_in[2], 32768);
    wcvt_k<<<cdiv(32768,256),B,0,stream>>>(Wc0p+32768,  w_in[5], 32768);
    wadd_k<<<cdiv(32768,256),B,0,stream>>>(Wc0p+65536,  w_in[4], w_in[7], 32768);
    wcvt_k<<<cdiv(32768,256),B,0,stream>>>(Wc0a,        w_in[8], 32768);
    wcvt_k<<<cdiv(32768,256),B,0,stream>>>(Wc0a+32768,  w_in[10], 32768);
    wcvt_k<<<cdiv(65536,256),B,0,stream>>>(Wc1,         w_in[11], 65536);
    wcvt_k<<<cdiv(65536,256),B,0,stream>>>(Wc1+65536,   w_in[14], 65536);
    wadd_k<<<cdiv(65536,256),B,0,stream>>>(Wc1+131072,  w_in[13], w_in[16], 65536);
    wcvt_k<<<cdiv(16384,256),B,0,stream>>>(Wcf,         w_in[20], 16384);
    bias_k<<<1,B,0,stream>>>(b0p, w_in[3],  w_in[6],  256);
    bias_k<<<1,B,0,stream>>>(b0a, w_in[9],  nullptr,  256);
    bias_k<<<1,B,0,stream>>>(b1,  w_in[12], w_in[15], 256);
    bias_k<<<1,B,0,stream>>>(bfin,w_in[21], nullptr,  64);
    repack_k<<<cdiv(12288,256),B,0,stream>>>(Wc0p, 384, 256, Wp0p);
    repack_k<<<cdiv( 8192,256),B,0,stream>>>(Wc0a, 256, 256, Wp0a);
    repack_k<<<cdiv(24576,256),B,0,stream>>>(Wc1,  768, 256, Wp1);
    repack_k<<<cdiv( 2048,256),B,0,stream>>>(Wcf,  256,  64, Wpf);
    int n2p = NP_ALL*128/2, n2a = NA_ALL*128/2;
    cvt2_k<<<cdiv(n2p,256),B,0,stream>>>((u32*)xpb, x_paper,  n2p);
    cvt2_k<<<cdiv(n2a,256),B,0,stream>>>((u32*)xab, x_author, n2a);

    // ---- phase 2: CSR build (histogram -> scan -> fill) ----
    hist_k<<<cdiv(nE_c1,256),B,0,stream>>>(e_c1+nE_c1, nE_c1, NP_H01, deg+SEG_C0);
    hist_k<<<cdiv(nE_c2,256),B,0,stream>>>(e_c2+nE_c2, nE_c2, NP_H01, deg+SEG_C0);
    hist_k<<<cdiv(nE_w1,256),B,0,stream>>>(e_w1+nE_w1, nE_w1, NP_H01, deg+SEG_W0);
    hist_k<<<cdiv(nE_w2,256),B,0,stream>>>(e_w2+nE_w2, nE_w2, NP_H01, deg+SEG_W0);
    hist_k<<<cdiv(nE_r1,256),B,0,stream>>>(e_r1+nE_r1, nE_r1, NA_H01, deg+SEG_R0);
    hist_k<<<cdiv(nE_r2,256),B,0,stream>>>(e_r2+nE_r2, nE_r2, NA_H01, deg+SEG_R0);
    hist_k<<<cdiv(nE_c1,256),B,0,stream>>>(e_c1+nE_c1, nE_c1, NP_H01, deg+SEG_C1);
    hist_k<<<cdiv(nE_w1,256),B,0,stream>>>(e_w1+nE_w1, nE_w1, NP_H01, deg+SEG_W1);
    scan1_k<<<SCAN_NBLK,B,0,stream>>>(deg, bsum);
    scan2_k<<<1,B,0,stream>>>(bsum, SCAN_NBLK);
    scan3_k<<<SCAN_NBLK,B,0,stream>>>(deg, bsum, rowptr, wp);
    fill_k<<<cdiv(nE_c1,256),B,0,stream>>>(e_c1, e_c1+nE_c1, nE_c1, NP_H01, wp+SEG_C0, pool);
    fill_k<<<cdiv(nE_c2,256),B,0,stream>>>(e_c2, e_c2+nE_c2, nE_c2, NP_H01, wp+SEG_C0, pool);
    fill_k<<<cdiv(nE_w1,256),B,0,stream>>>(e_w1, e_w1+nE_w1, nE_w1, NP_H01, wp+SEG_W0, pool);
    fill_k<<<cdiv(nE_w2,256),B,0,stream>>>(e_w2, e_w2+nE_w2, nE_w2, NP_H01, wp+SEG_W0, pool);
    fill_k<<<cdiv(nE_r1,256),B,0,stream>>>(e_r1, e_r1+nE_r1, nE_r1, NA_H01, wp+SEG_R0, pool);
    fill_k<<<cdiv(nE_r2,256),B,0,stream>>>(e_r2, e_r2+nE_r2, nE_r2, NA_H01, wp+SEG_R0, pool);
    fill_k<<<cdiv(nE_c1,256),B,0,stream>>>(e_c1, e_c1+nE_c1, nE_c1, NP_H01, wp+SEG_C1, pool);
    fill_k<<<cdiv(nE_w1,256),B,0,stream>>>(e_w1, e_w1+nE_w1, nE_w1, NP_H01, wp+SEG_W1, pool);

    // ---- phase 3: L0 gathers (build tiled Ap, Aa) ----
    gAp_k<<<cdiv((long)NP_H01*64,256),B,0,stream>>>(xpb, xab, rowptr, pool, Ap);
    gAa_k<<<cdiv((long)NA_H01*64,256),B,0,stream>>>(xpb, xab, rowptr, pool, Aa);

    // ---- phase 4: L0 GEMMs (xpb/xab dead now; xp lands tiled in A1 stages 8..11) ----
    {
        dim3 g(cdiv(NP_H01,128), 2);
        gemm4_k<2,2,4,4,true,false><<<g,B,0,stream>>>(Ap, NP_H01, 384, Wp0p, 16, b0p, A1, 0, NP_H01, 512);
    }
    {
        dim3 g(cdiv(NA_H01,128), 2);
        gemm4_k<2,2,4,4,true,false><<<g,B,0,stream>>>(Aa, NA_H01, 256, Wp0a, 16, b0a, xa, 256, 0, 0);
    }

    // ---- phase 5: L1 gather (A1 stages 0..7) ----
    gA1_k<<<cdiv((long)NP_H01*64,256),B,0,stream>>>(A1, xa, rowptr, pool, A1);

    // ---- phase 6: L1 GEMM (h1 tiled, overlays Ap) + final linear (f32 out) ----
    {
        dim3 g(cdiv(NP_H01,128), 2);
        gemm4_k<2,2,4,4,true,false><<<g,B,0,stream>>>(A1, NP_H01, 768, Wp1, 16, b1, h1, 0, NP_H01, 0);
    }
    {
        dim3 g(cdiv(NP_H01,256), 1);
        gemm4_k<4,1,4,4,false,true><<<g,B,0,stream>>>(h1, NP_H01, 256, Wpf, 4, bfin, out, 64, 0, 0);
    }
}